// Round 3
// baseline (333.290 us; speedup 1.0000x reference)
//
#include <hip/hip_runtime.h>

#define BB 2048
#define TT 2048
#define NP (TT/2)   // t-pairs
typedef unsigned short u16;
typedef unsigned int u32;

struct F4 { float f[4]; };

// ---------------------------------------------------------------------------
// p1: parallel pass. Reads all 7 inputs tiled 64x64; writes bhit/bdec final
// values; emits packed scan inputs transposed pair-wise:
//   exP  [P][B] float2  (ex for t=2p, 2p+1)
//   metaP[P][B] u32     (two u16: banchor[0:6] | anchor[7:13] | active<<14 | bevent<<15)
// LDS transpose, f32 [64][65] layout -> 2-way banks (free).
// ---------------------------------------------------------------------------
__global__ __launch_bounds__(256) void p1_tile(
    const float* __restrict__ ex_, const float* __restrict__ rnd_,
    const float* __restrict__ bud_, const float* __restrict__ sp_,
    const float* __restrict__ co_, const float* __restrict__ bd_,
    const float* __restrict__ pf_,
    float* __restrict__ bhit, float* __restrict__ bdec,
    float2* __restrict__ exP, u32* __restrict__ metaP)
{
    __shared__ float lex[64][65];
    __shared__ u32   lme[64][65];
    const int tid = threadIdx.x;
    const int tr = blockIdx.x & 31;   // row tile
    const int tc = blockIdx.x >> 5;   // t tile
    const int c4 = (tid & 15) << 2;
    const int r0 = tid >> 4;

#pragma unroll
    for (int rr = 0; rr < 4; ++rr) {
        const int rl = r0 + rr * 16;
        const size_t idx = (size_t)(tr * 64 + rl) * TT + (size_t)(tc * 64 + c4);
        F4 ex4 = *(const F4*)(ex_ + idx);
        F4 rn4 = *(const F4*)(rnd_ + idx);
        F4 bu4 = *(const F4*)(bud_ + idx);
        F4 sp4 = *(const F4*)(sp_ + idx);
        F4 co4 = *(const F4*)(co_ + idx);
        F4 bd4 = *(const F4*)(bd_ + idx);
        F4 pf4 = *(const F4*)(pf_ + idx);
        F4 bh;
#pragma unroll
        for (int j = 0; j < 4; ++j) {
            const bool active = (sp4.f[j] > 0.5f) || (co4.f[j] > 0.5f);
            const bool bevent = (bd4.f[j] >= 0.5f) || (pf4.f[j] > 0.5f);
            int ban = (int)fmaxf(bu4.f[j], 1.0f); if (ban > 127) ban = 127;
            int anc = (int)fmaxf(rn4.f[j], 1.0f); if (anc > 127) anc = 127;
            bh.f[j] = (active && bevent) ? 1.0f : 0.0f;
            lex[rl][c4 + j] = ex4.f[j];
            lme[rl][c4 + j] = (u32)(ban | (anc << 7) | (active ? 1 << 14 : 0) |
                                    (bevent ? 1 << 15 : 0));
        }
        *(F4*)(bhit + idx) = bh;
        *(F4*)(bdec + idx) = bh;
    }
    __syncthreads();
#pragma unroll
    for (int it = 0; it < 8; ++it) {
        const int idx = it * 256 + tid;
        const int r = idx & 63;       // row within tile (= lane -> coalesced)
        const int p = idx >> 6;       // pair within tile, 0..31
        float2 e;
        e.x = lex[r][2 * p]; e.y = lex[r][2 * p + 1];
        const u32 m = lme[r][2 * p] | (lme[r][2 * p + 1] << 16);
        const size_t o = (size_t)(tc * 32 + p) * BB + (size_t)(tr * 64 + r);
        exP[o] = e;
        metaP[o] = m;
    }
}

// ---------------------------------------------------------------------------
// p2: serial scan. lane = row, 32 blocks x 64 (1 wave/block). PF=16-pair
// register prefetch (pure-load vmcnt queue). Results buffered in a
// double-buffered LDS tile [64 rows][32 pairs]; every 32 pairs the tile is
// dumped transposed -> proj[B][T] with coalesced dwordx4 stores (p3 fused).
// step1 keeps reference-exact FP op order; med3 forms are bit-identical
// (lower<=upper by construction, no NaN) -- validated at absmax 0.0 in r2.
// ---------------------------------------------------------------------------
#define PF 16

__device__ __forceinline__ float step1(float ex, u32 m, float& carry, float& off) {
    const float banchor = (float)(m & 127);
    const float anchorf = (float)((m >> 7) & 127);
    const float scale   = (m & 0x8000u) ? 0.5f : 1.0f;   // bevent
    const float lower = fmaxf(ceilf(banchor - (3.0f + off)), 1.0f);
    const float upper = fmaxf(floorf(banchor + (3.0f - off)), lower);
    const float total = fmaxf(ex + carry, 0.0f);
    const float ff    = floorf(total + 0.5f);
    const float frames = __builtin_amdgcn_fmed3f(ff, lower, upper);
    const float nc = (total - frames) * scale;
    const float no = __builtin_amdgcn_fmed3f((off + (frames - banchor)) * scale,
                                             -3.0f, 3.0f);
    const bool act = (m & 0x4000u) != 0;
    carry = act ? nc : carry;
    off   = act ? no : off;
    return act ? frames : anchorf;
}

__global__ __launch_bounds__(64) void p2_scan(
    const float2* __restrict__ exP, const u32* __restrict__ metaP,
    const float* __restrict__ ci, const float* __restrict__ oi,
    float* __restrict__ proj, float* __restrict__ cout, float* __restrict__ oout)
{
    // [2 bufs][64 rows][34 pair-slots] float2; row stride 272B (16B aligned).
    __shared__ float2 t2[2][64][34];
    const int lane = threadIdx.x;
    const int row0 = blockIdx.x * 64;
    const int row = row0 + lane;
    float carry = ci[row];
    float off   = oi[row];
    const float2* pe = exP + row;
    const u32*    pm = metaP + row;

    float2 eq[PF]; u32 mq[PF];
#pragma unroll
    for (int i = 0; i < PF; ++i) {
        eq[i] = pe[(size_t)i * BB];
        mq[i] = pm[(size_t)i * BB];
    }

    int p = 0;
    for (; p < NP - PF; p += PF) {
        const int buf = (p >> 5) & 1;
#pragma unroll
        for (int i = 0; i < PF; ++i) {
            const float2 e = eq[i];
            const u32 m = mq[i];
            eq[i] = pe[(size_t)(p + PF + i) * BB];   // prefetch (in-bounds: p+PF+i < NP)
            mq[i] = pm[(size_t)(p + PF + i) * BB];
            float2 v;
            v.x = step1(e.x, m & 0xffffu, carry, off);
            v.y = step1(e.y, m >> 16, carry, off);
            t2[buf][lane][(p + i) & 31] = v;
        }
        if (((p + PF) & 31) == 0) {
            const int tbase = (p + PF - 32) * 2;
            const int bufd = ((p + PF - 32) >> 5) & 1;
            const float* tf = (const float*)&t2[bufd][0][0];
            const int rr = lane >> 4, cc4 = (lane & 15) << 2;
#pragma unroll
            for (int it = 0; it < 16; ++it) {
                const int r = it * 4 + rr;
                F4 o = *(const F4*)(tf + r * 68 + cc4);
                *(F4*)(proj + (size_t)(row0 + r) * TT + tbase + cc4) = o;
            }
        }
    }
    // epilogue chunk: no prefetch, then final dump
    {
        const int buf = (p >> 5) & 1;
#pragma unroll
        for (int i = 0; i < PF; ++i) {
            const float2 e = eq[i];
            const u32 m = mq[i];
            float2 v;
            v.x = step1(e.x, m & 0xffffu, carry, off);
            v.y = step1(e.y, m >> 16, carry, off);
            t2[buf][lane][(p + i) & 31] = v;
        }
        const int tbase = (p + PF - 32) * 2;
        const int bufd = ((p + PF - 32) >> 5) & 1;
        const float* tf = (const float*)&t2[bufd][0][0];
        const int rr = lane >> 4, cc4 = (lane & 15) << 2;
#pragma unroll
        for (int it = 0; it < 16; ++it) {
            const int r = it * 4 + rr;
            F4 o = *(const F4*)(tf + r * 68 + cc4);
            *(F4*)(proj + (size_t)(row0 + r) * TT + tbase + cc4) = o;
        }
    }
    cout[row] = carry;
    oout[row] = off;
}

// ---------------------------------------------------------------------------
// Fallback (ws too small): elementwise + direct-read scan (known-correct).
// ---------------------------------------------------------------------------
__global__ __launch_bounds__(256) void p1_lite(
    const float* __restrict__ rnd_, const float* __restrict__ sp_,
    const float* __restrict__ co_, const float* __restrict__ bd_,
    const float* __restrict__ pf_,
    float* __restrict__ proj, float* __restrict__ bhit, float* __restrict__ bdec)
{
    const size_t n4 = (size_t)BB * TT / 4;
    for (size_t i = (size_t)blockIdx.x * blockDim.x + threadIdx.x; i < n4;
         i += (size_t)gridDim.x * blockDim.x) {
        F4 rn4 = ((const F4*)rnd_)[i];
        F4 sp4 = ((const F4*)sp_)[i];
        F4 co4 = ((const F4*)co_)[i];
        F4 bd4 = ((const F4*)bd_)[i];
        F4 pf4 = ((const F4*)pf_)[i];
        F4 pj, bh;
#pragma unroll
        for (int j = 0; j < 4; ++j) {
            const bool active = (sp4.f[j] > 0.5f) || (co4.f[j] > 0.5f);
            const bool bevent = (bd4.f[j] >= 0.5f) || (pf4.f[j] > 0.5f);
            pj.f[j] = fmaxf(rn4.f[j], 1.0f);
            bh.f[j] = (active && bevent) ? 1.0f : 0.0f;
        }
        ((F4*)proj)[i] = pj;
        ((F4*)bhit)[i] = bh;
        ((F4*)bdec)[i] = bh;
    }
}

__global__ __launch_bounds__(64) void p2_direct(
    const float* __restrict__ ex_, const float* __restrict__ bud_,
    const float* __restrict__ sp_, const float* __restrict__ co_,
    const float* __restrict__ bd_, const float* __restrict__ pf_,
    const float* __restrict__ ci, const float* __restrict__ oi,
    float* __restrict__ proj, float* __restrict__ cout, float* __restrict__ oout)
{
    const int row = blockIdx.x * 64 + threadIdx.x;
    float carry = ci[row];
    float off   = oi[row];
    const size_t base = (size_t)row * TT;
    for (int t = 0; t < TT; ++t) {
        const float ex = ex_[base + t];
        const float banchor = fmaxf(bud_[base + t], 1.0f);
        const bool active = (sp_[base + t] > 0.5f) || (co_[base + t] > 0.5f);
        const bool bevent = (bd_[base + t] >= 0.5f) || (pf_[base + t] > 0.5f);
        const float scale = bevent ? 0.5f : 1.0f;
        const float lower = fmaxf(ceilf(banchor - (3.0f + off)), 1.0f);
        const float upper = fmaxf(floorf(banchor + (3.0f - off)), lower);
        const float total = fmaxf(ex + carry, 0.0f);
        const float frames = fminf(fmaxf(floorf(total + 0.5f), lower), upper);
        const float nc = (total - frames) * scale;
        float no = (off + (frames - banchor)) * scale;
        no = fminf(fmaxf(no, -3.0f), 3.0f);
        if (active) {
            proj[base + t] = frames;
            carry = nc;
            off = no;
        }
    }
    cout[row] = carry;
    oout[row] = off;
}

// ---------------------------------------------------------------------------
extern "C" void kernel_launch(void* const* d_in, const int* in_sizes, int n_in,
                              void* d_out, int out_size, void* d_ws, size_t ws_size,
                              hipStream_t stream) {
    const float* ex  = (const float*)d_in[0];
    const float* rnd = (const float*)d_in[1];
    const float* bud = (const float*)d_in[2];
    const float* sp  = (const float*)d_in[3];
    const float* co  = (const float*)d_in[4];
    const float* bd  = (const float*)d_in[5];
    const float* pf  = (const float*)d_in[6];
    const float* ci  = (const float*)d_in[7];
    const float* oi  = (const float*)d_in[8];

    float* proj = (float*)d_out;
    float* bhit = proj + (size_t)BB * TT;
    float* bdec = bhit + (size_t)BB * TT;
    float* cout = bdec + (size_t)BB * TT;
    float* oout = cout + BB;

    const size_t exP_bytes = (size_t)NP * BB * sizeof(float2);   // 16 MB
    const size_t meta_bytes = (size_t)NP * BB * sizeof(u32);     //  8 MB
    if (ws_size >= exP_bytes + meta_bytes) {
        float2* exP = (float2*)d_ws;
        u32* metaP  = (u32*)((char*)d_ws + exP_bytes);
        p1_tile<<<1024, 256, 0, stream>>>(ex, rnd, bud, sp, co, bd, pf,
                                          bhit, bdec, exP, metaP);
        p2_scan<<<32, 64, 0, stream>>>(exP, metaP, ci, oi, proj, cout, oout);
    } else {
        p1_lite<<<2048, 256, 0, stream>>>(rnd, sp, co, bd, pf, proj, bhit, bdec);
        p2_direct<<<32, 64, 0, stream>>>(ex, bud, sp, co, bd, pf, ci, oi,
                                         proj, cout, oout);
    }
}